// Round 9
// baseline (495.045 us; speedup 1.0000x reference)
//
#include <hip/hip_runtime.h>

#define N_NODES 100000
#define N_EDGES 1600000
#define D 64
#define N_GRAPHS 64
#define NBLK ((N_NODES + 255) / 256)   // 391 scan blocks
#define WTS 68                         // WT row stride (floats): conflict-benign

// ---------------- init: deg=1 (self loop), cnt=0, out=0 ----------------
__global__ void k_init(float* __restrict__ deg, int* __restrict__ cnt,
                       float* __restrict__ out) {
    int i = blockIdx.x * blockDim.x + threadIdx.x;
    if (i < N_NODES) { deg[i] = 1.0f; cnt[i] = 0; }
    if (i < N_GRAPHS * D) out[i] = 0.0f;
}

// ---------------- degree + in-edge count ----------------
__global__ void k_count_deg(const int* __restrict__ dst, const float* __restrict__ ew,
                            float* __restrict__ deg, int* __restrict__ cnt) {
    int e = blockIdx.x * blockDim.x + threadIdx.x;
    if (e < N_EDGES) {
        int d = dst[e];
        atomicAdd(&deg[d], ew[e]);
        atomicAdd(&cnt[d], 1);
    }
}

// ---------------- dinv (fused) + exclusive scan of cnt -> rowptr ------------
__global__ void k_scan1(const int* __restrict__ cnt, int* __restrict__ partial,
                        int* __restrict__ bsums, float* __restrict__ deg) {
    int t = threadIdx.x, b = blockIdx.x, i = b * 256 + t;
    if (i < N_NODES) {            // fused dinv: deg -> rsqrt(deg)
        float d = deg[i];
        deg[i] = d > 0.f ? rsqrtf(d) : 0.f;
    }
    int v = (i < N_NODES) ? cnt[i] : 0;
    int incl = v;
    int lane = t & 63;
#pragma unroll
    for (int off = 1; off < 64; off <<= 1) {
        int u = __shfl_up(incl, off);
        if (lane >= off) incl += u;
    }
    __shared__ int wsum[4];
    int w = t >> 6;
    if (lane == 63) wsum[w] = incl;
    __syncthreads();
    int add = 0;
    for (int k = 0; k < w; ++k) add += wsum[k];
    incl += add;
    if (i < N_NODES) partial[i] = incl;
    if (t == 255) bsums[b] = incl;
}

__global__ void k_scan2(int* __restrict__ bsums) {
    __shared__ int s[512];
    int t = threadIdx.x;
    s[t] = (t < NBLK) ? bsums[t] : 0;
    __syncthreads();
    for (int off = 1; off < 512; off <<= 1) {
        int u = (t >= off) ? s[t - off] : 0;
        __syncthreads();
        s[t] += u;
        __syncthreads();
    }
    if (t < NBLK) bsums[t] = (t == 0) ? 0 : s[t - 1];  // exclusive
}

__global__ void k_scan3(const int* __restrict__ partial, const int* __restrict__ cnt,
                        const int* __restrict__ bsums, int* __restrict__ rowptr,
                        int* __restrict__ cursor) {
    int i = blockIdx.x * 256 + threadIdx.x;
    if (i < N_NODES) {
        int excl = partial[i] - cnt[i] + bsums[blockIdx.x];
        rowptr[i] = excl;
        cursor[i] = excl;
    }
}

// ---------------- scatter edges into CSR (src, norm) grouped by dst ----------
__global__ void k_scatter(const int* __restrict__ src, const int* __restrict__ dst,
                          const float* __restrict__ ew, const float* __restrict__ dinv,
                          int* __restrict__ cursor, float2* __restrict__ csr) {
    int e = blockIdx.x * blockDim.x + threadIdx.x;
    if (e < N_EDGES) {
        int s = src[e];
        int d = dst[e];
        float nrm = dinv[s] * ew[e] * dinv[d];
        int pos = atomicAdd(&cursor[d], 1);
        csr[pos] = make_float2(__int_as_float(s), nrm);
    }
}

// ---------------- fused layer ----------------
// TWO rows per wave-iteration, interleaved in one instruction stream:
// 16 independent csr loads + 16 independent gathers in flight per pass
// (2x the MLP of one row). Fully-predicated unroll-8 passes per row
// (clamped index, zeroed weight). GEMM pairs both rows: the lane's
// W-column float4 is loaded once and used for both rows.
// LAYER==1: write relu(.)  LAYER==2: pool-atomicAdd relu(.) into out[batch].
template <int LAYER>
__global__ __launch_bounds__(256) void k_layer(
        const float* __restrict__ in, const float* __restrict__ W,
        const float* __restrict__ bias, const float* __restrict__ dinv,
        const int* __restrict__ rowptr, const int* __restrict__ cnt,
        const float2* __restrict__ csr, const int* __restrict__ batch,
        float* __restrict__ outp) {
    __shared__ float WTs[D * WTS];       // 17408 B transposed W
    __shared__ float aw[4][2 * D];       // 2 KB: per-wave 2-row staging
    __shared__ float bs[D];

    {   // stage W transposed: WTs[c*WTS + k] = W[k*D + c]
        int t = threadIdx.x;
#pragma unroll
        for (int i = 0; i < 16; ++i) {
            int idx = t + i * 256;
            int k = idx >> 6, c = idx & 63;
            WTs[c * WTS + k] = W[idx];
        }
        if (t < D) bs[t] = bias[t];
    }
    __syncthreads();

    const int lane = threadIdx.x & 63;
    const int wid  = threadIdx.x >> 6;
    float* awm = aw[wid];
    const float bl = bs[lane];

    int gw = (blockIdx.x * blockDim.x + threadIdx.x) >> 6;
    const int tw = (gridDim.x * blockDim.x) >> 6;
    const int NPAIR = N_NODES / 2;       // 50000

    for (int pr = gw; pr < NPAIR; pr += tw) {
        const int rowA = pr * 2;
        const int rowB = rowA + 1;
        const int stA = __builtin_amdgcn_readfirstlane(rowptr[rowA]);
        const int dgA = __builtin_amdgcn_readfirstlane(cnt[rowA]);
        const int stB = __builtin_amdgcn_readfirstlane(rowptr[rowB]);
        const int dgB = __builtin_amdgcn_readfirstlane(cnt[rowB]);
        const int clA = (dgA > 1 ? dgA - 1 : 0);   // clamp index
        const int clB = (dgB > 1 ? dgB - 1 : 0);
        float diA = dinv[rowA];
        float diB = dinv[rowB];
        float accA = in[rowA * D + lane] * (diA * diA);   // self-loops
        float accB = in[rowB * D + lane] * (diB * diB);

        const int dgmax = dgA > dgB ? dgA : dgB;
        const int passes = (dgmax + 7) >> 3;
        for (int p = 0; p < passes; ++p) {
            const int j = p * 8;
            // --- 16 independent csr loads (8 per row) ---
            float2 a0 = csr[stA + (j + 0 < clA ? j + 0 : clA)];
            float2 a1 = csr[stA + (j + 1 < clA ? j + 1 : clA)];
            float2 a2 = csr[stA + (j + 2 < clA ? j + 2 : clA)];
            float2 a3 = csr[stA + (j + 3 < clA ? j + 3 : clA)];
            float2 a4 = csr[stA + (j + 4 < clA ? j + 4 : clA)];
            float2 a5 = csr[stA + (j + 5 < clA ? j + 5 : clA)];
            float2 a6 = csr[stA + (j + 6 < clA ? j + 6 : clA)];
            float2 a7 = csr[stA + (j + 7 < clA ? j + 7 : clA)];
            float2 b0 = csr[stB + (j + 0 < clB ? j + 0 : clB)];
            float2 b1 = csr[stB + (j + 1 < clB ? j + 1 : clB)];
            float2 b2 = csr[stB + (j + 2 < clB ? j + 2 : clB)];
            float2 b3 = csr[stB + (j + 3 < clB ? j + 3 : clB)];
            float2 b4 = csr[stB + (j + 4 < clB ? j + 4 : clB)];
            float2 b5 = csr[stB + (j + 5 < clB ? j + 5 : clB)];
            float2 b6 = csr[stB + (j + 6 < clB ? j + 6 : clB)];
            float2 b7 = csr[stB + (j + 7 < clB ? j + 7 : clB)];
            // --- row A chain ---
            float wa0 = (j + 0 < dgA) ? a0.y : 0.f;
            float wa1 = (j + 1 < dgA) ? a1.y : 0.f;
            float wa2 = (j + 2 < dgA) ? a2.y : 0.f;
            float wa3 = (j + 3 < dgA) ? a3.y : 0.f;
            float wa4 = (j + 4 < dgA) ? a4.y : 0.f;
            float wa5 = (j + 5 < dgA) ? a5.y : 0.f;
            float wa6 = (j + 6 < dgA) ? a6.y : 0.f;
            float wa7 = (j + 7 < dgA) ? a7.y : 0.f;
            int sa0 = __builtin_amdgcn_readfirstlane(__float_as_int(a0.x));
            int sa1 = __builtin_amdgcn_readfirstlane(__float_as_int(a1.x));
            int sa2 = __builtin_amdgcn_readfirstlane(__float_as_int(a2.x));
            int sa3 = __builtin_amdgcn_readfirstlane(__float_as_int(a3.x));
            int sa4 = __builtin_amdgcn_readfirstlane(__float_as_int(a4.x));
            int sa5 = __builtin_amdgcn_readfirstlane(__float_as_int(a5.x));
            int sa6 = __builtin_amdgcn_readfirstlane(__float_as_int(a6.x));
            int sa7 = __builtin_amdgcn_readfirstlane(__float_as_int(a7.x));
            float va0 = in[sa0 * D + lane];
            float va1 = in[sa1 * D + lane];
            float va2 = in[sa2 * D + lane];
            float va3 = in[sa3 * D + lane];
            float va4 = in[sa4 * D + lane];
            float va5 = in[sa5 * D + lane];
            float va6 = in[sa6 * D + lane];
            float va7 = in[sa7 * D + lane];
            // --- row B chain (independent; overlaps row A's latency) ---
            float wb0 = (j + 0 < dgB) ? b0.y : 0.f;
            float wb1 = (j + 1 < dgB) ? b1.y : 0.f;
            float wb2 = (j + 2 < dgB) ? b2.y : 0.f;
            float wb3 = (j + 3 < dgB) ? b3.y : 0.f;
            float wb4 = (j + 4 < dgB) ? b4.y : 0.f;
            float wb5 = (j + 5 < dgB) ? b5.y : 0.f;
            float wb6 = (j + 6 < dgB) ? b6.y : 0.f;
            float wb7 = (j + 7 < dgB) ? b7.y : 0.f;
            int sb0 = __builtin_amdgcn_readfirstlane(__float_as_int(b0.x));
            int sb1 = __builtin_amdgcn_readfirstlane(__float_as_int(b1.x));
            int sb2 = __builtin_amdgcn_readfirstlane(__float_as_int(b2.x));
            int sb3 = __builtin_amdgcn_readfirstlane(__float_as_int(b3.x));
            int sb4 = __builtin_amdgcn_readfirstlane(__float_as_int(b4.x));
            int sb5 = __builtin_amdgcn_readfirstlane(__float_as_int(b5.x));
            int sb6 = __builtin_amdgcn_readfirstlane(__float_as_int(b6.x));
            int sb7 = __builtin_amdgcn_readfirstlane(__float_as_int(b7.x));
            float vb0 = in[sb0 * D + lane];
            float vb1 = in[sb1 * D + lane];
            float vb2 = in[sb2 * D + lane];
            float vb3 = in[sb3 * D + lane];
            float vb4 = in[sb4 * D + lane];
            float vb5 = in[sb5 * D + lane];
            float vb6 = in[sb6 * D + lane];
            float vb7 = in[sb7 * D + lane];
            accA = fmaf(va0, wa0, accA);
            accA = fmaf(va1, wa1, accA);
            accA = fmaf(va2, wa2, accA);
            accA = fmaf(va3, wa3, accA);
            accA = fmaf(va4, wa4, accA);
            accA = fmaf(va5, wa5, accA);
            accA = fmaf(va6, wa6, accA);
            accA = fmaf(va7, wa7, accA);
            accB = fmaf(vb0, wb0, accB);
            accB = fmaf(vb1, wb1, accB);
            accB = fmaf(vb2, wb2, accB);
            accB = fmaf(vb3, wb3, accB);
            accB = fmaf(vb4, wb4, accB);
            accB = fmaf(vb5, wb5, accB);
            accB = fmaf(vb6, wb6, accB);
            accB = fmaf(vb7, wb7, accB);
        }

        // ---- paired GEMM: r[lane] = sum_k acc[k] * W[k][lane], both rows ----
        awm[lane] = accA;
        awm[D + lane] = accB;   // same-wave LDS RAW; compiler inserts lgkmcnt
        float rA0 = 0.f, rA1 = 0.f, rA2 = 0.f, rA3 = 0.f;
        float rB0 = 0.f, rB1 = 0.f, rB2 = 0.f, rB3 = 0.f;
#pragma unroll
        for (int t = 0; t < 16; ++t) {
            float4 aA = *(const float4*)&awm[t * 4];               // broadcast
            float4 aB = *(const float4*)&awm[D + t * 4];           // broadcast
            float4 w  = *(const float4*)&WTs[lane * WTS + t * 4];  // shared
            rA0 = fmaf(aA.x, w.x, rA0);
            rA1 = fmaf(aA.y, w.y, rA1);
            rA2 = fmaf(aA.z, w.z, rA2);
            rA3 = fmaf(aA.w, w.w, rA3);
            rB0 = fmaf(aB.x, w.x, rB0);
            rB1 = fmaf(aB.y, w.y, rB1);
            rB2 = fmaf(aB.z, w.z, rB2);
            rB3 = fmaf(aB.w, w.w, rB3);
        }
        float rA = fmaxf((rA0 + rA1) + (rA2 + rA3) + bl, 0.f);
        float rB = fmaxf((rB0 + rB1) + (rB2 + rB3) + bl, 0.f);

        if (LAYER == 1) {
            outp[rowA * D + lane] = rA;
            outp[rowB * D + lane] = rB;
        } else {
            atomicAdd(&outp[batch[rowA] * D + lane], rA);
            atomicAdd(&outp[batch[rowB] * D + lane], rB);
        }
    }
}

// ---------------- finalize pool: divide by per-graph node count ----------------
__global__ void k_finalize(float* __restrict__ out, const int* __restrict__ batch) {
    int g = blockIdx.x;
    int lane = threadIdx.x;
    int lo = 0, hi = N_NODES;
    while (lo < hi) { int m = (lo + hi) >> 1; if (batch[m] < g) lo = m + 1; else hi = m; }
    int start = lo;
    hi = N_NODES;
    while (lo < hi) { int m = (lo + hi) >> 1; if (batch[m] < g + 1) lo = m + 1; else hi = m; }
    float c = (float)(lo - start);
    out[g * D + lane] /= fmaxf(c, 1.0f);
}

// ---------------- launch ----------------
extern "C" void kernel_launch(void* const* d_in, const int* in_sizes, int n_in,
                              void* d_out, int out_size, void* d_ws, size_t ws_size,
                              hipStream_t stream) {
    const float* x     = (const float*)d_in[0];
    const int*   ei    = (const int*)d_in[1];
    const int*   src   = ei;
    const int*   dst   = ei + N_EDGES;
    const int*   batch = (const int*)d_in[2];
    const float* ew    = (const float*)d_in[3];
    const float* W1    = (const float*)d_in[4];
    const float* b1    = (const float*)d_in[5];
    const float* W2    = (const float*)d_in[6];
    const float* b2    = (const float*)d_in[7];
    float* out = (float*)d_out;

    char* ws = (char*)d_ws;
    float*  bufA   = (float*)(ws);                    // 25.6 MB  h1
    float2* csr    = (float2*)(ws + 25600000);        // 12.8 MB  (src, norm)
    float*  deg    = (float*)(ws + 38400000);         // 400 KB   deg -> dinv
    int*    cnt    = (int*)(ws + 38800000);           // 400 KB
    int*    rowptr = (int*)(ws + 39200000);           // 400 KB
    int*    cursor = (int*)(ws + 39600000);           // 400 KB
    int*    bsums  = (int*)(ws + 40000000);           // 2 KB

    // normalization + CSR build
    k_init<<<NBLK, 256, 0, stream>>>(deg, cnt, out);
    k_count_deg<<<(N_EDGES + 255) / 256, 256, 0, stream>>>(dst, ew, deg, cnt);
    k_scan1<<<NBLK, 256, 0, stream>>>(cnt, rowptr, bsums, deg);   // + fused dinv
    k_scan2<<<1, 512, 0, stream>>>(bsums);
    k_scan3<<<NBLK, 256, 0, stream>>>(rowptr, cnt, bsums, rowptr, cursor);
    k_scatter<<<(N_EDGES + 255) / 256, 256, 0, stream>>>(src, dst, ew, deg, cursor, csr);

    // layer 1: bufA = relu((A x) W1 + b1)
    k_layer<1><<<2048, 256, 0, stream>>>(x, W1, b1, deg, rowptr, cnt, csr, batch, bufA);
    // layer 2 + pool-sum: out[g] += relu((A bufA) W2 + b2)
    k_layer<2><<<2048, 256, 0, stream>>>(bufA, W2, b2, deg, rowptr, cnt, csr, batch, out);
    // mean
    k_finalize<<<N_GRAPHS, D, 0, stream>>>(out, batch);
}